// Round 3
// baseline (208.528 us; speedup 1.0000x reference)
//
#include <hip/hip_runtime.h>
#include <hip/hip_bf16.h>

// NTM cell on MI355X. B=2048, IN=64, CTRL=512, M=1024, V=64, OUT=64.
// 4 dispatches: k_pre (convert + read_prev GEMM), k_gates (+fused LSTM),
// k_heads (read/write/erase/add + out_h), k_tail (softmax + read_new + out).
// All GEMMs NT bf16 MFMA 16x16x32, BK=128, LDS row stride 136.

typedef unsigned short u16;
typedef __attribute__((ext_vector_type(8))) short bf16x8;
typedef __attribute__((ext_vector_type(4))) float f32x4;

#define MFMA_BF16(a, b, c) __builtin_amdgcn_mfma_f32_16x16x32_bf16((a), (b), (c), 0, 0, 0)
#define LDW 136

__device__ __forceinline__ u16 f2bf(float f) {
    union { float f; unsigned int u; } a; a.f = f;
    return (u16)((a.u + 0x7FFFu + ((a.u >> 16) & 1u)) >> 16);
}

__device__ __forceinline__ void pack_store4(float a0, float a1, float a2, float a3, u16* d) {
    union { __hip_bfloat162 h[2]; uint2 u; } cv;
    cv.h[0] = __float22bfloat162_rn(make_float2(a0, a1));
    cv.h[1] = __float22bfloat162_rn(make_float2(a2, a3));
    *(uint2*)d = cv.u;
}

__device__ __forceinline__ void cvt4(const float* __restrict__ s, u16* __restrict__ d) {
    float4 v = *(const float4*)s;
    pack_store4(v.x, v.y, v.z, v.w, d);
}

__device__ __forceinline__ uint4 cvt8u(const float* __restrict__ s) {
    float4 v0 = *(const float4*)(s);
    float4 v1 = *(const float4*)(s + 4);
    union { __hip_bfloat162 h[4]; uint4 u; } r;
    r.h[0] = __float22bfloat162_rn(make_float2(v0.x, v0.y));
    r.h[1] = __float22bfloat162_rn(make_float2(v0.z, v0.w));
    r.h[2] = __float22bfloat162_rn(make_float2(v1.x, v1.y));
    r.h[3] = __float22bfloat162_rn(make_float2(v1.z, v1.w));
    return r.u;
}

__device__ __forceinline__ void store16bf(u16* __restrict__ d, const float* __restrict__ v) {
    union { __hip_bfloat162 h[8]; uint4 u[2]; } cv;
#pragma unroll
    for (int j = 0; j < 8; ++j) cv.h[j] = __float22bfloat162_rn(make_float2(v[2 * j], v[2 * j + 1]));
    *(uint4*)d = cv.u[0];
    *(uint4*)(d + 8) = cv.u[1];
}

__device__ __forceinline__ float sigf(float x) { return 1.f / (1.f + __expf(-x)); }
__device__ __forceinline__ float fast_tanh(float x) { return 1.f - 2.f / (__expf(2.f * x) + 1.f); }

__device__ __forceinline__ float wave_max(float v) {
#pragma unroll
    for (int o = 32; o > 0; o >>= 1) v = fmaxf(v, __shfl_xor(v, o, 64));
    return v;
}
__device__ __forceinline__ float wave_sum(float v) {
#pragma unroll
    for (int o = 32; o > 0; o >>= 1) v += __shfl_xor(v, o, 64);
    return v;
}

// ---------------------------------------------------------------------------
// k_pre: blocks 0..31 = read_prev GEMM (reads rwp & memory fp32 directly,
// converts during staging; memory transposed via LDS write). Blocks 32.. do
// fp32->bf16 conversion / reorder jobs (one float4 job per thread).
// ---------------------------------------------------------------------------
__global__ __launch_bounds__(256) void k_pre(
    const float* __restrict__ x, const float* __restrict__ h_prev, const float* __restrict__ rwp,
    const float* __restrict__ memory, const float* __restrict__ W_ih, const float* __restrict__ W_hh,
    const float* __restrict__ W_read, const float* __restrict__ W_write, const float* __restrict__ W_erase,
    const float* __restrict__ W_add, const float* __restrict__ W_out,
    u16* inp_h, u16* wcat, u16* Wcat2, u16* Wo_rn, u16* memt, float* rp)
{
    __shared__ u16 As[64 * LDW];
    __shared__ u16 Bs[64 * LDW];
    const int tid = threadIdx.x;

    if (blockIdx.x < 32) {
        // read_prev: rp = rwp @ memory  (BM=64, K=1024, BK=128)
        const int w = tid >> 6, lane = tid & 63;
        const int lrow = lane & 15, lq = lane >> 4;
        const int m0 = blockIdx.x * 64;
        const int m_loc = tid >> 1, v0 = (tid & 1) * 32;
        f32x4 acc[4] = {};
        for (int kt = 0; kt < 8; ++kt) {
#pragma unroll
            for (int i = 0; i < 4; ++i) {
                int idx = i * 256 + tid, r = idx >> 4, c = (idx & 15) * 8;
                *(uint4*)(&As[r * LDW + c]) = cvt8u(rwp + (m0 + r) * 1024 + kt * 128 + c);
            }
            // B-tile transpose: memory[kt*128 + m_loc, v0..v0+32] -> Bs[v][m_loc]
#pragma unroll
            for (int j = 0; j < 8; ++j) {
                float4 q = *(const float4*)(memory + (kt * 128 + m_loc) * 64 + v0 + 4 * j);
                Bs[(v0 + 4 * j + 0) * LDW + m_loc] = f2bf(q.x);
                Bs[(v0 + 4 * j + 1) * LDW + m_loc] = f2bf(q.y);
                Bs[(v0 + 4 * j + 2) * LDW + m_loc] = f2bf(q.z);
                Bs[(v0 + 4 * j + 3) * LDW + m_loc] = f2bf(q.w);
            }
            __syncthreads();
#pragma unroll
            for (int kk = 0; kk < 128; kk += 32) {
                bf16x8 a  = *(const bf16x8*)(&As[(16 * w + lrow) * LDW + kk + 8 * lq]);
                bf16x8 b0 = *(const bf16x8*)(&Bs[(lrow) * LDW + kk + 8 * lq]);
                bf16x8 b1 = *(const bf16x8*)(&Bs[(16 + lrow) * LDW + kk + 8 * lq]);
                bf16x8 b2 = *(const bf16x8*)(&Bs[(32 + lrow) * LDW + kk + 8 * lq]);
                bf16x8 b3 = *(const bf16x8*)(&Bs[(48 + lrow) * LDW + kk + 8 * lq]);
                acc[0] = MFMA_BF16(a, b0, acc[0]);
                acc[1] = MFMA_BF16(a, b1, acc[1]);
                acc[2] = MFMA_BF16(a, b2, acc[2]);
                acc[3] = MFMA_BF16(a, b3, acc[3]);
            }
            __syncthreads();
        }
#pragma unroll
        for (int nj = 0; nj < 4; ++nj)
#pragma unroll
            for (int r = 0; r < 4; ++r) {
                int row = m0 + 16 * w + 4 * lq + r, col = 16 * nj + lrow;
                rp[row * 64 + col] = acc[nj][r];
            }
        return;
    }

    int t = (blockIdx.x - 32) * 256 + tid;
    if (t < 32768) { int r = t >> 4, c = (t & 15) * 4; cvt4(x + r * 64 + c, inp_h + r * 576 + c); return; }
    t -= 32768;
    if (t < 262144) { int r = t >> 7, c = (t & 127) * 4; cvt4(h_prev + r * 512 + c, inp_h + r * 576 + 64 + c); return; }
    t -= 262144;
    if (t < 65536) {  // W_ih: row reorder (gate interleave) + col swap (rp|x)
        int r = t >> 5, c = (t & 31) * 4;
        int g = r >> 9, j = r & 511;
        int rn = (j >> 4) * 64 + (g << 4) + (j & 15);
        int cd = (c < 64) ? c + 64 : c - 64;
        cvt4(W_ih + r * 128 + c, wcat + rn * 640 + cd); return;
    }
    t -= 65536;
    if (t < 262144) {  // W_hh: row reorder
        int r = t >> 7, c = (t & 127) * 4;
        int g = r >> 9, j = r & 511;
        int rn = (j >> 4) * 64 + (g << 4) + (j & 15);
        cvt4(W_hh + r * 512 + c, wcat + rn * 640 + 128 + c); return;
    }
    t -= 262144;
    if (t < 131072) { cvt4(W_read + t * 4, Wcat2 + t * 4); return; }
    t -= 131072;
    if (t < 131072) { cvt4(W_write + t * 4, Wcat2 + 524288 + t * 4); return; }
    t -= 131072;
    if (t < 8192) { cvt4(W_erase + t * 4, Wcat2 + 1048576 + t * 4); return; }
    t -= 8192;
    if (t < 8192) { cvt4(W_add + t * 4, Wcat2 + 1081344 + t * 4); return; }
    t -= 8192;
    if (t < 9216) {  // W_out: h-part -> Wcat2 rows 2176..2239, rn-part -> Wo_rn
        int r = t / 144, c = (t % 144) * 4;
        if (c < 512) cvt4(W_out + r * 576 + c, Wcat2 + (2176 + r) * 512 + c);
        else         cvt4(W_out + r * 576 + c, Wo_rn + r * 64 + (c - 512));
        return;
    }
    t -= 9216;
    if (t < 16384) {  // memory^T -> memt (64 x 1024)
        int v = t >> 8, m = (t & 255) * 4;
        pack_store4(memory[m * 64 + v], memory[(m + 1) * 64 + v],
                    memory[(m + 2) * 64 + v], memory[(m + 3) * 64 + v], memt + v * 1024 + m);
    }
}

// ---------------------------------------------------------------------------
// gates GEMM + fused LSTM. A-K layout: [read_prev(64, fp32 cvt) | x(64) | h_prev(512)].
// wcat rows pre-reordered so block col = gate*16 + (j & 15), j = bn*16 + lrow.
// ---------------------------------------------------------------------------
__global__ __launch_bounds__(256) void k_gates(const u16* __restrict__ inp_h, const float* __restrict__ rp,
                                               const u16* __restrict__ wcat,
                                               const float* __restrict__ b_ih, const float* __restrict__ b_hh,
                                               const float* __restrict__ c_prev, u16* __restrict__ hrn)
{
    __shared__ u16 As[128 * LDW];
    __shared__ u16 Bs[64 * LDW];
    const int tid = threadIdx.x, w = tid >> 6, lane = tid & 63;
    const int lrow = lane & 15, lq = lane >> 4;
    const int m0 = blockIdx.x * 128, bn = blockIdx.y;
    const u16* Bbase = wcat + bn * 64 * 640;
    f32x4 acc[2][4] = {};
    for (int kt = 0; kt < 5; ++kt) {
#pragma unroll
        for (int i = 0; i < 8; ++i) {
            int idx = i * 256 + tid, r = idx >> 4, c = (idx & 15) * 8;
            int ak = kt * 128 + c;
            uint4 v;
            if (ak < 64) v = cvt8u(rp + (m0 + r) * 64 + ak);
            else         v = *(const uint4*)(inp_h + (m0 + r) * 576 + (ak - 64));
            *(uint4*)(&As[r * LDW + c]) = v;
        }
#pragma unroll
        for (int i = 0; i < 4; ++i) {
            int idx = i * 256 + tid, r = idx >> 4, c = (idx & 15) * 8;
            *(uint4*)(&Bs[r * LDW + c]) = *(const uint4*)(Bbase + r * 640 + kt * 128 + c);
        }
        __syncthreads();
#pragma unroll
        for (int kk = 0; kk < 128; kk += 32) {
            bf16x8 a0 = *(const bf16x8*)(&As[(32 * w + lrow) * LDW + kk + 8 * lq]);
            bf16x8 a1 = *(const bf16x8*)(&As[(32 * w + 16 + lrow) * LDW + kk + 8 * lq]);
            bf16x8 b0 = *(const bf16x8*)(&Bs[(lrow) * LDW + kk + 8 * lq]);
            bf16x8 b1 = *(const bf16x8*)(&Bs[(16 + lrow) * LDW + kk + 8 * lq]);
            bf16x8 b2 = *(const bf16x8*)(&Bs[(32 + lrow) * LDW + kk + 8 * lq]);
            bf16x8 b3 = *(const bf16x8*)(&Bs[(48 + lrow) * LDW + kk + 8 * lq]);
            acc[0][0] = MFMA_BF16(a0, b0, acc[0][0]);
            acc[0][1] = MFMA_BF16(a0, b1, acc[0][1]);
            acc[0][2] = MFMA_BF16(a0, b2, acc[0][2]);
            acc[0][3] = MFMA_BF16(a0, b3, acc[0][3]);
            acc[1][0] = MFMA_BF16(a1, b0, acc[1][0]);
            acc[1][1] = MFMA_BF16(a1, b1, acc[1][1]);
            acc[1][2] = MFMA_BF16(a1, b2, acc[1][2]);
            acc[1][3] = MFMA_BF16(a1, b3, acc[1][3]);
        }
        __syncthreads();
    }
    const int j = bn * 16 + lrow;
    const float bI = b_ih[j] + b_hh[j];
    const float bF = b_ih[512 + j] + b_hh[512 + j];
    const float bG = b_ih[1024 + j] + b_hh[1024 + j];
    const float bO = b_ih[1536 + j] + b_hh[1536 + j];
#pragma unroll
    for (int mi = 0; mi < 2; ++mi)
#pragma unroll
        for (int r = 0; r < 4; ++r) {
            int row = m0 + 32 * w + 16 * mi + 4 * lq + r;
            float ig = sigf(acc[mi][0][r] + bI);
            float fg = sigf(acc[mi][1][r] + bF);
            float gg = fast_tanh(acc[mi][2][r] + bG);
            float og = sigf(acc[mi][3][r] + bO);
            float c = fg * c_prev[row * 512 + j] + ig * gg;
            hrn[row * 512 + j] = f2bf(og * fast_tanh(c));
        }
}

// ---------------------------------------------------------------------------
// heads: [pre_read | pre_write | erase | add | out_h] = h @ Wcat2^T + biases.
// grid (16, 35): bn<16 pre_r, <32 pre_w, 32 erase(sig), 33 add(tanh), 34 out_h.
// ---------------------------------------------------------------------------
__global__ __launch_bounds__(256) void k_heads(const u16* __restrict__ hrn, const u16* __restrict__ Wcat2,
                                               const float* __restrict__ b_read, const float* __restrict__ b_write,
                                               const float* __restrict__ b_erase, const float* __restrict__ b_add,
                                               const float* __restrict__ b_out,
                                               float* __restrict__ pre_r, float* __restrict__ pre_w,
                                               float* __restrict__ erase, float* __restrict__ add,
                                               float* __restrict__ out_h)
{
    __shared__ u16 As[128 * LDW];
    __shared__ u16 Bs[64 * LDW];
    const int tid = threadIdx.x, w = tid >> 6, lane = tid & 63;
    const int lrow = lane & 15, lq = lane >> 4;
    const int m0 = blockIdx.x * 128, bn = blockIdx.y;
    const u16* Bbase = Wcat2 + bn * 64 * 512;
    f32x4 acc[2][4] = {};
    for (int kt = 0; kt < 4; ++kt) {
#pragma unroll
        for (int i = 0; i < 8; ++i) {
            int idx = i * 256 + tid, r = idx >> 4, c = (idx & 15) * 8;
            *(uint4*)(&As[r * LDW + c]) = *(const uint4*)(hrn + (m0 + r) * 512 + kt * 128 + c);
        }
#pragma unroll
        for (int i = 0; i < 4; ++i) {
            int idx = i * 256 + tid, r = idx >> 4, c = (idx & 15) * 8;
            *(uint4*)(&Bs[r * LDW + c]) = *(const uint4*)(Bbase + r * 512 + kt * 128 + c);
        }
        __syncthreads();
#pragma unroll
        for (int kk = 0; kk < 128; kk += 32) {
            bf16x8 a0 = *(const bf16x8*)(&As[(32 * w + lrow) * LDW + kk + 8 * lq]);
            bf16x8 a1 = *(const bf16x8*)(&As[(32 * w + 16 + lrow) * LDW + kk + 8 * lq]);
            bf16x8 b0 = *(const bf16x8*)(&Bs[(lrow) * LDW + kk + 8 * lq]);
            bf16x8 b1 = *(const bf16x8*)(&Bs[(16 + lrow) * LDW + kk + 8 * lq]);
            bf16x8 b2 = *(const bf16x8*)(&Bs[(32 + lrow) * LDW + kk + 8 * lq]);
            bf16x8 b3 = *(const bf16x8*)(&Bs[(48 + lrow) * LDW + kk + 8 * lq]);
            acc[0][0] = MFMA_BF16(a0, b0, acc[0][0]);
            acc[0][1] = MFMA_BF16(a0, b1, acc[0][1]);
            acc[0][2] = MFMA_BF16(a0, b2, acc[0][2]);
            acc[0][3] = MFMA_BF16(a0, b3, acc[0][3]);
            acc[1][0] = MFMA_BF16(a1, b0, acc[1][0]);
            acc[1][1] = MFMA_BF16(a1, b1, acc[1][1]);
            acc[1][2] = MFMA_BF16(a1, b2, acc[1][2]);
            acc[1][3] = MFMA_BF16(a1, b3, acc[1][3]);
        }
        __syncthreads();
    }
#pragma unroll
    for (int mi = 0; mi < 2; ++mi)
#pragma unroll
        for (int nj = 0; nj < 4; ++nj)
#pragma unroll
            for (int r = 0; r < 4; ++r) {
                int row = m0 + 32 * w + 16 * mi + 4 * lq + r;
                int col = bn * 64 + 16 * nj + lrow;
                float v = acc[mi][nj][r];
                if (bn < 16)       pre_r[row * 1024 + col] = v + b_read[col];
                else if (bn < 32)  pre_w[row * 1024 + (col - 1024)] = v + b_write[col - 1024];
                else if (bn == 32) erase[row * 64 + (col - 2048)] = sigf(v + b_erase[col - 2048]);
                else if (bn == 33) add[row * 64 + (col - 2112)] = fast_tanh(v + b_add[col - 2112]);
                else               out_h[row * 64 + (col - 2176)] = v + b_out[col - 2176];
            }
}

// ---------------------------------------------------------------------------
// k_tail: per 64-row block: dual softmax -> rw, rw2 (global, XCD-local L2);
// read_new GEMM (K=1024); out = out_h + rn @ Wo_rn^T.
// ---------------------------------------------------------------------------
__global__ __launch_bounds__(256) void k_tail(const float* __restrict__ pre_r, const float* __restrict__ pre_w,
                                              const u16* __restrict__ memt, const u16* __restrict__ Wo_rn,
                                              const float* __restrict__ erase, const float* __restrict__ add,
                                              const float* __restrict__ out_h,
                                              u16* __restrict__ rw_bf, u16* __restrict__ rw2_bf,
                                              float* __restrict__ out)
{
    __shared__ u16 As1[64 * LDW];
    __shared__ u16 As2[64 * LDW];
    __shared__ u16 Bs[64 * LDW];
    __shared__ u16 rnS[64 * 72];
    __shared__ float s_sh[64];
    const int tid = threadIdx.x, w = tid >> 6, lane = tid & 63;
    const int lrow = lane & 15, lq = lane >> 4;
    const int m0 = blockIdx.x * 64;

    // Phase 1: dual softmax, wave w handles rows w*16 .. w*16+15; lane owns cols lane*16..+16
    for (int i = 0; i < 16; ++i) {
        int row_l = w * 16 + i, row_g = m0 + row_l;
        const float* prb = pre_r + row_g * 1024 + lane * 16;
        const float* pwb = pre_w + row_g * 1024 + lane * 16;
        float vr[16], vw[16];
#pragma unroll
        for (int q = 0; q < 4; ++q) {
            float4 a = *(const float4*)(prb + 4 * q);
            float4 b = *(const float4*)(pwb + 4 * q);
            vr[4 * q] = a.x; vr[4 * q + 1] = a.y; vr[4 * q + 2] = a.z; vr[4 * q + 3] = a.w;
            vw[4 * q] = b.x; vw[4 * q + 1] = b.y; vw[4 * q + 2] = b.z; vw[4 * q + 3] = b.w;
        }
        float mr = vr[0], mw = vw[0];
#pragma unroll
        for (int q = 1; q < 16; ++q) { mr = fmaxf(mr, vr[q]); mw = fmaxf(mw, vw[q]); }
        mr = wave_max(mr); mw = wave_max(mw);
        float sr = 0.f, sw = 0.f;
#pragma unroll
        for (int q = 0; q < 16; ++q) {
            vr[q] = __expf(vr[q] - mr); sr += vr[q];
            vw[q] = __expf(vw[q] - mw); sw += vw[q];
        }
        sr = wave_sum(sr); sw = wave_sum(sw);
        float isr = 1.f / sr, isw = 1.f / sw, ss = 0.f;
        float r2[16];
#pragma unroll
        for (int q = 0; q < 16; ++q) {
            vr[q] *= isr;
            r2[q] = vr[q] * (vw[q] * isw);
            ss += r2[q];
        }
        store16bf(rw_bf + row_g * 1024 + lane * 16, vr);
        store16bf(rw2_bf + row_g * 1024 + lane * 16, r2);
        ss = wave_sum(ss);
        if (lane == 0) s_sh[row_l] = ss;
    }
    __syncthreads();

    // Phase 2: rn = rw@memt^T - erase*(rw2@memt^T) + add*s   (K=1024)
    f32x4 acc1[4] = {}, acc2[4] = {};
    for (int kt = 0; kt < 8; ++kt) {
#pragma unroll
        for (int i = 0; i < 4; ++i) {
            int idx = i * 256 + tid, r = idx >> 4, c = (idx & 15) * 8;
            *(uint4*)(&As1[r * LDW + c]) = *(const uint4*)(rw_bf + (m0 + r) * 1024 + kt * 128 + c);
            *(uint4*)(&As2[r * LDW + c]) = *(const uint4*)(rw2_bf + (m0 + r) * 1024 + kt * 128 + c);
            *(uint4*)(&Bs[r * LDW + c])  = *(const uint4*)(memt + r * 1024 + kt * 128 + c);
        }
        __syncthreads();
#pragma unroll
        for (int kk = 0; kk < 128; kk += 32) {
            bf16x8 a  = *(const bf16x8*)(&As1[(16 * w + lrow) * LDW + kk + 8 * lq]);
            bf16x8 a2 = *(const bf16x8*)(&As2[(16 * w + lrow) * LDW + kk + 8 * lq]);
            bf16x8 b0 = *(const bf16x8*)(&Bs[(lrow) * LDW + kk + 8 * lq]);
            bf16x8 b1 = *(const bf16x8*)(&Bs[(16 + lrow) * LDW + kk + 8 * lq]);
            bf16x8 b2 = *(const bf16x8*)(&Bs[(32 + lrow) * LDW + kk + 8 * lq]);
            bf16x8 b3 = *(const bf16x8*)(&Bs[(48 + lrow) * LDW + kk + 8 * lq]);
            acc1[0] = MFMA_BF16(a, b0, acc1[0]);
            acc1[1] = MFMA_BF16(a, b1, acc1[1]);
            acc1[2] = MFMA_BF16(a, b2, acc1[2]);
            acc1[3] = MFMA_BF16(a, b3, acc1[3]);
            acc2[0] = MFMA_BF16(a2, b0, acc2[0]);
            acc2[1] = MFMA_BF16(a2, b1, acc2[1]);
            acc2[2] = MFMA_BF16(a2, b2, acc2[2]);
            acc2[3] = MFMA_BF16(a2, b3, acc2[3]);
        }
        __syncthreads();
    }
#pragma unroll
    for (int nj = 0; nj < 4; ++nj)
#pragma unroll
        for (int r = 0; r < 4; ++r) {
            int row_l = 16 * w + 4 * lq + r, col = 16 * nj + lrow;
            int row_g = m0 + row_l;
            float rn = acc1[nj][r] - erase[row_g * 64 + col] * acc2[nj][r]
                     + add[row_g * 64 + col] * s_sh[row_l];
            rnS[row_l * 72 + col] = f2bf(rn);
        }
    __syncthreads();

    // Phase 3: out = out_h + rn @ Wo_rn^T  (K=64)
#pragma unroll
    for (int i = 0; i < 2; ++i) {
        int idx = i * 256 + tid, r = idx >> 3, c = (idx & 7) * 8;
        *(uint4*)(&Bs[r * LDW + c]) = *(const uint4*)(Wo_rn + r * 64 + c);
    }
    __syncthreads();
    f32x4 acc3[4] = {};
#pragma unroll
    for (int kk = 0; kk < 64; kk += 32) {
        bf16x8 a  = *(const bf16x8*)(&rnS[(16 * w + lrow) * 72 + kk + 8 * lq]);
        bf16x8 b0 = *(const bf16x8*)(&Bs[(lrow) * LDW + kk + 8 * lq]);
        bf16x8 b1 = *(const bf16x8*)(&Bs[(16 + lrow) * LDW + kk + 8 * lq]);
        bf16x8 b2 = *(const bf16x8*)(&Bs[(32 + lrow) * LDW + kk + 8 * lq]);
        bf16x8 b3 = *(const bf16x8*)(&Bs[(48 + lrow) * LDW + kk + 8 * lq]);
        acc3[0] = MFMA_BF16(a, b0, acc3[0]);
        acc3[1] = MFMA_BF16(a, b1, acc3[1]);
        acc3[2] = MFMA_BF16(a, b2, acc3[2]);
        acc3[3] = MFMA_BF16(a, b3, acc3[3]);
    }
#pragma unroll
    for (int nj = 0; nj < 4; ++nj)
#pragma unroll
        for (int r = 0; r < 4; ++r) {
            int row_g = m0 + 16 * w + 4 * lq + r, col = 16 * nj + lrow;
            out[row_g * 64 + col] = acc3[nj][r] + out_h[row_g * 64 + col];
        }
}

extern "C" void kernel_launch(void* const* d_in, const int* in_sizes, int n_in,
                              void* d_out, int out_size, void* d_ws, size_t ws_size,
                              hipStream_t stream)
{
    const float* x        = (const float*)d_in[0];
    const float* h_prev   = (const float*)d_in[1];
    const float* c_prev   = (const float*)d_in[2];
    const float* rwp      = (const float*)d_in[3];
    const float* memory   = (const float*)d_in[4];
    const float* W_ih     = (const float*)d_in[5];
    const float* b_ih     = (const float*)d_in[6];
    const float* W_hh     = (const float*)d_in[7];
    const float* b_hh     = (const float*)d_in[8];
    const float* W_read   = (const float*)d_in[9];
    const float* b_read   = (const float*)d_in[10];
    const float* W_write  = (const float*)d_in[11];
    const float* b_write  = (const float*)d_in[12];
    const float* W_erase  = (const float*)d_in[13];
    const float* b_erase  = (const float*)d_in[14];
    const float* W_add    = (const float*)d_in[15];
    const float* b_add    = (const float*)d_in[16];
    const float* W_out    = (const float*)d_in[17];
    const float* b_out    = (const float*)d_in[18];
    float* out = (float*)d_out;

    char* wsp = (char*)d_ws;
    u16*   inp_h  = (u16*)(wsp + 0);           // 2048x576 bf16 [x | h_prev]
    u16*   wcat   = (u16*)(wsp + 2359296);     // 2048x640 bf16 gates weights (reordered)
    u16*   memt   = (u16*)(wsp + 4980736);     // 64x1024 bf16 memory^T
    u16*   Wcat2  = (u16*)(wsp + 5111808);     // 2240x512 bf16 [Wr;Ww;We;Wa;Wout_h]
    u16*   Wo_rn  = (u16*)(wsp + 7405568);     // 64x64 bf16 (W_out rn-part)
    float* rp     = (float*)(wsp + 7413760);   // 2048x64 fp32
    u16*   hrn    = (u16*)(wsp + 7938048);     // 2048x512 bf16 (h)
    float* pre_r  = (float*)(wsp + 10035200);  // 2048x1024 fp32
    float* pre_w  = (float*)(wsp + 18423808);  // 2048x1024 fp32
    float* erase  = (float*)(wsp + 26812416);  // 2048x64 fp32
    float* add    = (float*)(wsp + 27336704);  // 2048x64 fp32
    float* out_h  = (float*)(wsp + 27860992);  // 2048x64 fp32
    u16*   rw_bf  = (u16*)(wsp + 28385280);    // 2048x1024 bf16
    u16*   rw2_bf = (u16*)(wsp + 32579584);    // 2048x1024 bf16

    k_pre<<<3652, 256, 0, stream>>>(x, h_prev, rwp, memory, W_ih, W_hh, W_read, W_write,
                                    W_erase, W_add, W_out,
                                    inp_h, wcat, Wcat2, Wo_rn, memt, rp);
    k_gates<<<dim3(16, 32), 256, 0, stream>>>(inp_h, rp, wcat, b_ih, b_hh, c_prev, hrn);
    k_heads<<<dim3(16, 35), 256, 0, stream>>>(hrn, Wcat2, b_read, b_write, b_erase, b_add, b_out,
                                              pre_r, pre_w, erase, add, out_h);
    k_tail<<<32, 256, 0, stream>>>(pre_r, pre_w, memt, Wo_rn, erase, add, out_h,
                                   rw_bf, rw2_bf, out);
}

// Round 4
// 159.782 us; speedup vs baseline: 1.3051x; 1.3051x over previous
//
#include <hip/hip_runtime.h>
#include <hip/hip_bf16.h>

// NTM cell on MI355X. B=2048, IN=64, CTRL=512, M=1024, V=64, OUT=64.
// 5 dispatches: k_pre (convert + split-K read_prev), k_gates (+fused LSTM),
// k_heads (heads + out_h -> d_out), k_softmax (dual, bf16), k_rnout
// (split-K read_new fused with out-GEMM, atomicAdd into d_out).
// All GEMMs NT bf16 MFMA 16x16x32, BK=128, LDS row stride 136.

typedef unsigned short u16;
typedef __attribute__((ext_vector_type(8))) short bf16x8;
typedef __attribute__((ext_vector_type(4))) float f32x4;

#define MFMA_BF16(a, b, c) __builtin_amdgcn_mfma_f32_16x16x32_bf16((a), (b), (c), 0, 0, 0)
#define LDW 136

__device__ __forceinline__ u16 f2bf(float f) {
    union { float f; unsigned int u; } a; a.f = f;
    return (u16)((a.u + 0x7FFFu + ((a.u >> 16) & 1u)) >> 16);
}

__device__ __forceinline__ void pack_store4(float a0, float a1, float a2, float a3, u16* d) {
    union { __hip_bfloat162 h[2]; uint2 u; } cv;
    cv.h[0] = __float22bfloat162_rn(make_float2(a0, a1));
    cv.h[1] = __float22bfloat162_rn(make_float2(a2, a3));
    *(uint2*)d = cv.u;
}

__device__ __forceinline__ void cvt4(const float* __restrict__ s, u16* __restrict__ d) {
    float4 v = *(const float4*)s;
    pack_store4(v.x, v.y, v.z, v.w, d);
}

__device__ __forceinline__ uint4 cvt8u(const float* __restrict__ s) {
    float4 v0 = *(const float4*)(s);
    float4 v1 = *(const float4*)(s + 4);
    union { __hip_bfloat162 h[4]; uint4 u; } r;
    r.h[0] = __float22bfloat162_rn(make_float2(v0.x, v0.y));
    r.h[1] = __float22bfloat162_rn(make_float2(v0.z, v0.w));
    r.h[2] = __float22bfloat162_rn(make_float2(v1.x, v1.y));
    r.h[3] = __float22bfloat162_rn(make_float2(v1.z, v1.w));
    return r.u;
}

// sum of 4 fp32 partial slabs (each 2048*64 elems apart) -> 8 bf16
__device__ __forceinline__ uint4 cvt8u_sum4(const float* __restrict__ p, int off) {
    float4 a0 = *(const float4*)(p + off);
    float4 a1 = *(const float4*)(p + 131072 + off);
    float4 a2 = *(const float4*)(p + 262144 + off);
    float4 a3 = *(const float4*)(p + 393216 + off);
    float4 b0 = *(const float4*)(p + off + 4);
    float4 b1 = *(const float4*)(p + 131072 + off + 4);
    float4 b2 = *(const float4*)(p + 262144 + off + 4);
    float4 b3 = *(const float4*)(p + 393216 + off + 4);
    float4 s0{a0.x + a1.x + a2.x + a3.x, a0.y + a1.y + a2.y + a3.y,
              a0.z + a1.z + a2.z + a3.z, a0.w + a1.w + a2.w + a3.w};
    float4 s1{b0.x + b1.x + b2.x + b3.x, b0.y + b1.y + b2.y + b3.y,
              b0.z + b1.z + b2.z + b3.z, b0.w + b1.w + b2.w + b3.w};
    union { __hip_bfloat162 h[4]; uint4 u; } r;
    r.h[0] = __float22bfloat162_rn(make_float2(s0.x, s0.y));
    r.h[1] = __float22bfloat162_rn(make_float2(s0.z, s0.w));
    r.h[2] = __float22bfloat162_rn(make_float2(s1.x, s1.y));
    r.h[3] = __float22bfloat162_rn(make_float2(s1.z, s1.w));
    return r.u;
}

__device__ __forceinline__ float4 bf4_to_f4(uint2 u) {
    union { uint2 u; __hip_bfloat162 h[2]; } c; c.u = u;
    float2 a = __bfloat1622float2(c.h[0]);
    float2 b = __bfloat1622float2(c.h[1]);
    return float4{a.x, a.y, b.x, b.y};
}

__device__ __forceinline__ float sigf(float x) { return 1.f / (1.f + __expf(-x)); }
__device__ __forceinline__ float fast_tanh(float x) { return 1.f - 2.f / (__expf(2.f * x) + 1.f); }

__device__ __forceinline__ float wave_max(float v) {
#pragma unroll
    for (int o = 32; o > 0; o >>= 1) v = fmaxf(v, __shfl_xor(v, o, 64));
    return v;
}
__device__ __forceinline__ float wave_sum(float v) {
#pragma unroll
    for (int o = 32; o > 0; o >>= 1) v += __shfl_xor(v, o, 64);
    return v;
}

// ---------------------------------------------------------------------------
// k_pre: blocks 0..127 = split-K read_prev GEMM (32 m-blocks x 4 K-chunks of
// 256), partials -> rp[ks]. Blocks 128.. = fp32->bf16 convert/reorder jobs.
// ---------------------------------------------------------------------------
__global__ __launch_bounds__(256) void k_pre(
    const float* __restrict__ x, const float* __restrict__ h_prev, const float* __restrict__ rwp,
    const float* __restrict__ memory, const float* __restrict__ W_ih, const float* __restrict__ W_hh,
    const float* __restrict__ W_read, const float* __restrict__ W_write, const float* __restrict__ W_erase,
    const float* __restrict__ W_add, const float* __restrict__ W_out,
    u16* inp_h, u16* wcat, u16* Wcat2, u16* Wo_rn, u16* memt, float* rp)
{
    __shared__ u16 As[64 * LDW];
    __shared__ u16 Bs[64 * LDW];
    const int tid = threadIdx.x;

    if (blockIdx.x < 128) {
        const int mb = blockIdx.x & 31, ks = blockIdx.x >> 5;
        const int w = tid >> 6, lane = tid & 63;
        const int lrow = lane & 15, lq = lane >> 4;
        const int m0 = mb * 64, k0 = ks * 256;
        const int m_loc = tid >> 1, v0 = (tid & 1) * 32;
        f32x4 acc[4] = {};
        for (int kt = 0; kt < 2; ++kt) {
#pragma unroll
            for (int i = 0; i < 4; ++i) {
                int idx = i * 256 + tid, r = idx >> 4, c = (idx & 15) * 8;
                *(uint4*)(&As[r * LDW + c]) = cvt8u(rwp + (m0 + r) * 1024 + k0 + kt * 128 + c);
            }
            // B-tile transpose: memory[k0+kt*128+m_loc, v0..v0+32] -> Bs[v][m_loc]
#pragma unroll
            for (int j = 0; j < 8; ++j) {
                float4 q = *(const float4*)(memory + (k0 + kt * 128 + m_loc) * 64 + v0 + 4 * j);
                Bs[(v0 + 4 * j + 0) * LDW + m_loc] = f2bf(q.x);
                Bs[(v0 + 4 * j + 1) * LDW + m_loc] = f2bf(q.y);
                Bs[(v0 + 4 * j + 2) * LDW + m_loc] = f2bf(q.z);
                Bs[(v0 + 4 * j + 3) * LDW + m_loc] = f2bf(q.w);
            }
            __syncthreads();
#pragma unroll
            for (int kk = 0; kk < 128; kk += 32) {
                bf16x8 a  = *(const bf16x8*)(&As[(16 * w + lrow) * LDW + kk + 8 * lq]);
                bf16x8 b0 = *(const bf16x8*)(&Bs[(lrow) * LDW + kk + 8 * lq]);
                bf16x8 b1 = *(const bf16x8*)(&Bs[(16 + lrow) * LDW + kk + 8 * lq]);
                bf16x8 b2 = *(const bf16x8*)(&Bs[(32 + lrow) * LDW + kk + 8 * lq]);
                bf16x8 b3 = *(const bf16x8*)(&Bs[(48 + lrow) * LDW + kk + 8 * lq]);
                acc[0] = MFMA_BF16(a, b0, acc[0]);
                acc[1] = MFMA_BF16(a, b1, acc[1]);
                acc[2] = MFMA_BF16(a, b2, acc[2]);
                acc[3] = MFMA_BF16(a, b3, acc[3]);
            }
            __syncthreads();
        }
        float* rps = rp + ks * 131072;
#pragma unroll
        for (int nj = 0; nj < 4; ++nj)
#pragma unroll
            for (int r = 0; r < 4; ++r) {
                int row = m0 + 16 * w + 4 * lq + r, col = 16 * nj + lrow;
                rps[row * 64 + col] = acc[nj][r];
            }
        return;
    }

    int t = (blockIdx.x - 128) * 256 + tid;
    if (t < 32768) { int r = t >> 4, c = (t & 15) * 4; cvt4(x + r * 64 + c, inp_h + r * 576 + c); return; }
    t -= 32768;
    if (t < 262144) { int r = t >> 7, c = (t & 127) * 4; cvt4(h_prev + r * 512 + c, inp_h + r * 576 + 64 + c); return; }
    t -= 262144;
    if (t < 65536) {  // W_ih: row reorder (gate interleave) + col swap (rp|x)
        int r = t >> 5, c = (t & 31) * 4;
        int g = r >> 9, j = r & 511;
        int rn = (j >> 4) * 64 + (g << 4) + (j & 15);
        int cd = (c < 64) ? c + 64 : c - 64;
        cvt4(W_ih + r * 128 + c, wcat + rn * 640 + cd); return;
    }
    t -= 65536;
    if (t < 262144) {  // W_hh: row reorder
        int r = t >> 7, c = (t & 127) * 4;
        int g = r >> 9, j = r & 511;
        int rn = (j >> 4) * 64 + (g << 4) + (j & 15);
        cvt4(W_hh + r * 512 + c, wcat + rn * 640 + 128 + c); return;
    }
    t -= 262144;
    if (t < 131072) { cvt4(W_read + t * 4, Wcat2 + t * 4); return; }
    t -= 131072;
    if (t < 131072) { cvt4(W_write + t * 4, Wcat2 + 524288 + t * 4); return; }
    t -= 131072;
    if (t < 8192) { cvt4(W_erase + t * 4, Wcat2 + 1048576 + t * 4); return; }
    t -= 8192;
    if (t < 8192) { cvt4(W_add + t * 4, Wcat2 + 1081344 + t * 4); return; }
    t -= 8192;
    if (t < 9216) {  // W_out: h-part -> Wcat2 rows 2176..2239, rn-part -> Wo_rn
        int r = t / 144, c = (t % 144) * 4;
        if (c < 512) cvt4(W_out + r * 576 + c, Wcat2 + (2176 + r) * 512 + c);
        else         cvt4(W_out + r * 576 + c, Wo_rn + r * 64 + (c - 512));
        return;
    }
    t -= 9216;
    if (t < 16384) {  // memory^T -> memt (64 x 1024)
        int v = t >> 8, m = (t & 255) * 4;
        pack_store4(memory[m * 64 + v], memory[(m + 1) * 64 + v],
                    memory[(m + 2) * 64 + v], memory[(m + 3) * 64 + v], memt + v * 1024 + m);
    }
}

// ---------------------------------------------------------------------------
// gates GEMM + fused LSTM. A-K layout: [read_prev(64, sum of 4 fp32 partials)
// | x(64) | h_prev(512)]. wcat rows pre-reordered: block col = gate*16+(j&15).
// ---------------------------------------------------------------------------
__global__ __launch_bounds__(256) void k_gates(const u16* __restrict__ inp_h, const float* __restrict__ rp,
                                               const u16* __restrict__ wcat,
                                               const float* __restrict__ b_ih, const float* __restrict__ b_hh,
                                               const float* __restrict__ c_prev, u16* __restrict__ hrn)
{
    __shared__ u16 As[128 * LDW];
    __shared__ u16 Bs[64 * LDW];
    const int tid = threadIdx.x, w = tid >> 6, lane = tid & 63;
    const int lrow = lane & 15, lq = lane >> 4;
    const int m0 = blockIdx.x * 128, bn = blockIdx.y;
    const u16* Bbase = wcat + bn * 64 * 640;
    f32x4 acc[2][4] = {};
    for (int kt = 0; kt < 5; ++kt) {
#pragma unroll
        for (int i = 0; i < 8; ++i) {
            int idx = i * 256 + tid, r = idx >> 4, c = (idx & 15) * 8;
            int ak = kt * 128 + c;
            uint4 v;
            if (ak < 64) v = cvt8u_sum4(rp, (m0 + r) * 64 + ak);
            else         v = *(const uint4*)(inp_h + (m0 + r) * 576 + (ak - 64));
            *(uint4*)(&As[r * LDW + c]) = v;
        }
#pragma unroll
        for (int i = 0; i < 4; ++i) {
            int idx = i * 256 + tid, r = idx >> 4, c = (idx & 15) * 8;
            *(uint4*)(&Bs[r * LDW + c]) = *(const uint4*)(Bbase + r * 640 + kt * 128 + c);
        }
        __syncthreads();
#pragma unroll
        for (int kk = 0; kk < 128; kk += 32) {
            bf16x8 a0 = *(const bf16x8*)(&As[(32 * w + lrow) * LDW + kk + 8 * lq]);
            bf16x8 a1 = *(const bf16x8*)(&As[(32 * w + 16 + lrow) * LDW + kk + 8 * lq]);
            bf16x8 b0 = *(const bf16x8*)(&Bs[(lrow) * LDW + kk + 8 * lq]);
            bf16x8 b1 = *(const bf16x8*)(&Bs[(16 + lrow) * LDW + kk + 8 * lq]);
            bf16x8 b2 = *(const bf16x8*)(&Bs[(32 + lrow) * LDW + kk + 8 * lq]);
            bf16x8 b3 = *(const bf16x8*)(&Bs[(48 + lrow) * LDW + kk + 8 * lq]);
            acc[0][0] = MFMA_BF16(a0, b0, acc[0][0]);
            acc[0][1] = MFMA_BF16(a0, b1, acc[0][1]);
            acc[0][2] = MFMA_BF16(a0, b2, acc[0][2]);
            acc[0][3] = MFMA_BF16(a0, b3, acc[0][3]);
            acc[1][0] = MFMA_BF16(a1, b0, acc[1][0]);
            acc[1][1] = MFMA_BF16(a1, b1, acc[1][1]);
            acc[1][2] = MFMA_BF16(a1, b2, acc[1][2]);
            acc[1][3] = MFMA_BF16(a1, b3, acc[1][3]);
        }
        __syncthreads();
    }
    const int j = bn * 16 + lrow;
    const float bI = b_ih[j] + b_hh[j];
    const float bF = b_ih[512 + j] + b_hh[512 + j];
    const float bG = b_ih[1024 + j] + b_hh[1024 + j];
    const float bO = b_ih[1536 + j] + b_hh[1536 + j];
#pragma unroll
    for (int mi = 0; mi < 2; ++mi)
#pragma unroll
        for (int r = 0; r < 4; ++r) {
            int row = m0 + 32 * w + 16 * mi + 4 * lq + r;
            float ig = sigf(acc[mi][0][r] + bI);
            float fg = sigf(acc[mi][1][r] + bF);
            float gg = fast_tanh(acc[mi][2][r] + bG);
            float og = sigf(acc[mi][3][r] + bO);
            float c = fg * c_prev[row * 512 + j] + ig * gg;
            hrn[row * 512 + j] = f2bf(og * fast_tanh(c));
        }
}

// ---------------------------------------------------------------------------
// heads: [pre_read | pre_write | erase | add | out_h] = h @ Wcat2^T + biases.
// grid (16, 35). pre_r/pre_w stored bf16. bn==34 writes out_h directly to out.
// ---------------------------------------------------------------------------
__global__ __launch_bounds__(256) void k_heads(const u16* __restrict__ hrn, const u16* __restrict__ Wcat2,
                                               const float* __restrict__ b_read, const float* __restrict__ b_write,
                                               const float* __restrict__ b_erase, const float* __restrict__ b_add,
                                               const float* __restrict__ b_out,
                                               u16* __restrict__ pre_r, u16* __restrict__ pre_w,
                                               float* __restrict__ erase, float* __restrict__ add,
                                               float* __restrict__ out)
{
    __shared__ u16 As[128 * LDW];
    __shared__ u16 Bs[64 * LDW];
    const int tid = threadIdx.x, w = tid >> 6, lane = tid & 63;
    const int lrow = lane & 15, lq = lane >> 4;
    const int m0 = blockIdx.x * 128, bn = blockIdx.y;
    const u16* Bbase = Wcat2 + bn * 64 * 512;
    f32x4 acc[2][4] = {};
    for (int kt = 0; kt < 4; ++kt) {
#pragma unroll
        for (int i = 0; i < 8; ++i) {
            int idx = i * 256 + tid, r = idx >> 4, c = (idx & 15) * 8;
            *(uint4*)(&As[r * LDW + c]) = *(const uint4*)(hrn + (m0 + r) * 512 + kt * 128 + c);
        }
#pragma unroll
        for (int i = 0; i < 4; ++i) {
            int idx = i * 256 + tid, r = idx >> 4, c = (idx & 15) * 8;
            *(uint4*)(&Bs[r * LDW + c]) = *(const uint4*)(Bbase + r * 512 + kt * 128 + c);
        }
        __syncthreads();
#pragma unroll
        for (int kk = 0; kk < 128; kk += 32) {
            bf16x8 a0 = *(const bf16x8*)(&As[(32 * w + lrow) * LDW + kk + 8 * lq]);
            bf16x8 a1 = *(const bf16x8*)(&As[(32 * w + 16 + lrow) * LDW + kk + 8 * lq]);
            bf16x8 b0 = *(const bf16x8*)(&Bs[(lrow) * LDW + kk + 8 * lq]);
            bf16x8 b1 = *(const bf16x8*)(&Bs[(16 + lrow) * LDW + kk + 8 * lq]);
            bf16x8 b2 = *(const bf16x8*)(&Bs[(32 + lrow) * LDW + kk + 8 * lq]);
            bf16x8 b3 = *(const bf16x8*)(&Bs[(48 + lrow) * LDW + kk + 8 * lq]);
            acc[0][0] = MFMA_BF16(a0, b0, acc[0][0]);
            acc[0][1] = MFMA_BF16(a0, b1, acc[0][1]);
            acc[0][2] = MFMA_BF16(a0, b2, acc[0][2]);
            acc[0][3] = MFMA_BF16(a0, b3, acc[0][3]);
            acc[1][0] = MFMA_BF16(a1, b0, acc[1][0]);
            acc[1][1] = MFMA_BF16(a1, b1, acc[1][1]);
            acc[1][2] = MFMA_BF16(a1, b2, acc[1][2]);
            acc[1][3] = MFMA_BF16(a1, b3, acc[1][3]);
        }
        __syncthreads();
    }
#pragma unroll
    for (int mi = 0; mi < 2; ++mi)
#pragma unroll
        for (int nj = 0; nj < 4; ++nj)
#pragma unroll
            for (int r = 0; r < 4; ++r) {
                int row = m0 + 32 * w + 16 * mi + 4 * lq + r;
                int col = bn * 64 + 16 * nj + lrow;
                float v = acc[mi][nj][r];
                if (bn < 16)       pre_r[row * 1024 + col] = f2bf(v + b_read[col]);
                else if (bn < 32)  pre_w[row * 1024 + (col - 1024)] = f2bf(v + b_write[col - 1024]);
                else if (bn == 32) erase[row * 64 + (col - 2048)] = sigf(v + b_erase[col - 2048]);
                else if (bn == 33) add[row * 64 + (col - 2112)] = fast_tanh(v + b_add[col - 2112]);
                else               out[row * 64 + (col - 2176)] = v + b_out[col - 2176];
            }
}

// ---------------------------------------------------------------------------
// dual softmax over M=1024 (bf16 in/out); one block per row.
// emits rw_bf, rw2_bf = rw*ww, s[b] = sum(rw*ww)
// ---------------------------------------------------------------------------
__global__ __launch_bounds__(256) void k_softmax(const u16* __restrict__ pr, const u16* __restrict__ pw,
                                                 u16* __restrict__ rw_bf, u16* __restrict__ rw2_bf,
                                                 float* __restrict__ s)
{
    int b = blockIdx.x, tid = threadIdx.x, w = tid >> 6, lane = tid & 63;
    float4 vr = bf4_to_f4(*(const uint2*)(pr + b * 1024 + tid * 4));
    float4 vw = bf4_to_f4(*(const uint2*)(pw + b * 1024 + tid * 4));
    float mr = fmaxf(fmaxf(vr.x, vr.y), fmaxf(vr.z, vr.w));
    float mw = fmaxf(fmaxf(vw.x, vw.y), fmaxf(vw.z, vw.w));
    mr = wave_max(mr); mw = wave_max(mw);
    __shared__ float red[4][4];
    if (lane == 0) { red[0][w] = mr; red[1][w] = mw; }
    __syncthreads();
    mr = fmaxf(fmaxf(red[0][0], red[0][1]), fmaxf(red[0][2], red[0][3]));
    mw = fmaxf(fmaxf(red[1][0], red[1][1]), fmaxf(red[1][2], red[1][3]));
    float er[4] = {__expf(vr.x - mr), __expf(vr.y - mr), __expf(vr.z - mr), __expf(vr.w - mr)};
    float ew[4] = {__expf(vw.x - mw), __expf(vw.y - mw), __expf(vw.z - mw), __expf(vw.w - mw)};
    float sr = er[0] + er[1] + er[2] + er[3];
    float sw = ew[0] + ew[1] + ew[2] + ew[3];
    sr = wave_sum(sr); sw = wave_sum(sw);
    __syncthreads();
    if (lane == 0) { red[2][w] = sr; red[3][w] = sw; }
    __syncthreads();
    sr = red[2][0] + red[2][1] + red[2][2] + red[2][3];
    sw = red[3][0] + red[3][1] + red[3][2] + red[3][3];
    float isr = 1.f / sr, isw = 1.f / sw, ss = 0.f;
    float a[4], r2[4];
#pragma unroll
    for (int i = 0; i < 4; ++i) {
        a[i] = er[i] * isr;
        r2[i] = a[i] * (ew[i] * isw);
        ss += r2[i];
    }
    pack_store4(a[0], a[1], a[2], a[3], rw_bf + b * 1024 + tid * 4);
    pack_store4(r2[0], r2[1], r2[2], r2[3], rw2_bf + b * 1024 + tid * 4);
    ss = wave_sum(ss);
    __syncthreads();
    if (lane == 0) red[0][w] = ss;
    __syncthreads();
    if (tid == 0) s[b] = red[0][0] + red[0][1] + red[0][2] + red[0][3];
}

// ---------------------------------------------------------------------------
// k_rnout: split-K fused read_new + out-GEMM. grid (64 m-blocks x 4 K-chunks).
// partial rn tile (32x64) = rw@memt^T - erase*(rw2@memt^T) [+ add*s on kh==0],
// then partial_out = partial_rn @ Wo_rn^T, atomicAdd into out (pre-seeded by
// k_heads with out_h + b_out). Both terms linear in K-partials -> exact.
// ---------------------------------------------------------------------------
__global__ __launch_bounds__(256) void k_rnout(const u16* __restrict__ rw, const u16* __restrict__ rw2,
                                               const u16* __restrict__ memt, const u16* __restrict__ Wo_rn,
                                               const float* __restrict__ erase, const float* __restrict__ add,
                                               const float* __restrict__ s, float* __restrict__ out)
{
    __shared__ u16 As1[32 * LDW];
    __shared__ u16 As2[32 * LDW];
    __shared__ u16 Bs[64 * LDW];
    __shared__ u16 Ps[32 * 72];
    const int tid = threadIdx.x, w = tid >> 6, lane = tid & 63;
    const int lrow = lane & 15, lq = lane >> 4;
    const int m0 = blockIdx.x * 32, k0 = blockIdx.y * 256;
    const int mt = w & 1, nb = (w >> 1) * 2;

    f32x4 a1[2] = {}, a2[2] = {};
    for (int kt = 0; kt < 2; ++kt) {
#pragma unroll
        for (int i = 0; i < 2; ++i) {
            int idx = i * 256 + tid, r = idx >> 4, c = (idx & 15) * 8;
            *(uint4*)(&As1[r * LDW + c]) = *(const uint4*)(rw + (m0 + r) * 1024 + k0 + kt * 128 + c);
            *(uint4*)(&As2[r * LDW + c]) = *(const uint4*)(rw2 + (m0 + r) * 1024 + k0 + kt * 128 + c);
        }
#pragma unroll
        for (int i = 0; i < 4; ++i) {
            int idx = i * 256 + tid, r = idx >> 4, c = (idx & 15) * 8;
            *(uint4*)(&Bs[r * LDW + c]) = *(const uint4*)(memt + r * 1024 + k0 + kt * 128 + c);
        }
        __syncthreads();
#pragma unroll
        for (int kk = 0; kk < 128; kk += 32) {
            bf16x8 a  = *(const bf16x8*)(&As1[(16 * mt + lrow) * LDW + kk + 8 * lq]);
            bf16x8 c2 = *(const bf16x8*)(&As2[(16 * mt + lrow) * LDW + kk + 8 * lq]);
            bf16x8 b0 = *(const bf16x8*)(&Bs[(16 * nb + lrow) * LDW + kk + 8 * lq]);
            bf16x8 b1 = *(const bf16x8*)(&Bs[(16 * (nb + 1) + lrow) * LDW + kk + 8 * lq]);
            a1[0] = MFMA_BF16(a, b0, a1[0]);
            a1[1] = MFMA_BF16(a, b1, a1[1]);
            a2[0] = MFMA_BF16(c2, b0, a2[0]);
            a2[1] = MFMA_BF16(c2, b1, a2[1]);
        }
        __syncthreads();
    }
    // stage Wo_rn into Bs while writing partial rn (bf16) to Ps
#pragma unroll
    for (int i = 0; i < 2; ++i) {
        int idx = i * 256 + tid, r = idx >> 3, c = (idx & 7) * 8;
        *(uint4*)(&Bs[r * LDW + c]) = *(const uint4*)(Wo_rn + r * 64 + c);
    }
#pragma unroll
    for (int j = 0; j < 2; ++j)
#pragma unroll
        for (int r = 0; r < 4; ++r) {
            int row_l = 16 * mt + 4 * lq + r, col = 16 * (nb + j) + lrow;
            int row_g = m0 + row_l;
            float p = a1[j][r] - erase[row_g * 64 + col] * a2[j][r];
            if (blockIdx.y == 0) p += add[row_g * 64 + col] * s[row_g];
            Ps[row_l * 72 + col] = f2bf(p);
        }
    __syncthreads();
    // out-GEMM: (32 x 64) @ Wo_rn^T (64 x 64), K = 64
    f32x4 o[2] = {};
#pragma unroll
    for (int kk = 0; kk < 64; kk += 32) {
        bf16x8 a  = *(const bf16x8*)(&Ps[(16 * mt + lrow) * 72 + kk + 8 * lq]);
        bf16x8 b0 = *(const bf16x8*)(&Bs[(16 * nb + lrow) * LDW + kk + 8 * lq]);
        bf16x8 b1 = *(const bf16x8*)(&Bs[(16 * (nb + 1) + lrow) * LDW + kk + 8 * lq]);
        o[0] = MFMA_BF16(a, b0, o[0]);
        o[1] = MFMA_BF16(a, b1, o[1]);
    }
#pragma unroll
    for (int j = 0; j < 2; ++j)
#pragma unroll
        for (int r = 0; r < 4; ++r) {
            int row_g = m0 + 16 * mt + 4 * lq + r, col = 16 * (nb + j) + lrow;
            atomicAdd(&out[row_g * 64 + col], o[j][r]);
        }
}

extern "C" void kernel_launch(void* const* d_in, const int* in_sizes, int n_in,
                              void* d_out, int out_size, void* d_ws, size_t ws_size,
                              hipStream_t stream)
{
    const float* x        = (const float*)d_in[0];
    const float* h_prev   = (const float*)d_in[1];
    const float* c_prev   = (const float*)d_in[2];
    const float* rwp      = (const float*)d_in[3];
    const float* memory   = (const float*)d_in[4];
    const float* W_ih     = (const float*)d_in[5];
    const float* b_ih     = (const float*)d_in[6];
    const float* W_hh     = (const float*)d_in[7];
    const float* b_hh     = (const float*)d_in[8];
    const float* W_read   = (const float*)d_in[9];
    const float* b_read   = (const float*)d_in[10];
    const float* W_write  = (const float*)d_in[11];
    const float* b_write  = (const float*)d_in[12];
    const float* W_erase  = (const float*)d_in[13];
    const float* b_erase  = (const float*)d_in[14];
    const float* W_add    = (const float*)d_in[15];
    const float* b_add    = (const float*)d_in[16];
    const float* W_out    = (const float*)d_in[17];
    const float* b_out    = (const float*)d_in[18];
    float* out = (float*)d_out;

    char* wsp = (char*)d_ws;
    u16*   inp_h  = (u16*)(wsp + 0);           // 2048x576 bf16 [x | h_prev]
    u16*   wcat   = (u16*)(wsp + 2359296);     // 2048x640 bf16 gates weights (reordered)
    u16*   memt   = (u16*)(wsp + 4980736);     // 64x1024 bf16 memory^T
    u16*   Wcat2  = (u16*)(wsp + 5111808);     // 2240x512 bf16 [Wr;Ww;We;Wa;Wout_h]
    u16*   Wo_rn  = (u16*)(wsp + 7405568);     // 64x64 bf16 (W_out rn-part)
    float* rp     = (float*)(wsp + 7413760);   // 4 x 2048x64 fp32 split-K partials
    u16*   hrn    = (u16*)(wsp + 9510912);     // 2048x512 bf16 (h)
    u16*   pre_r  = (u16*)(wsp + 11608064);    // 2048x1024 bf16
    u16*   pre_w  = (u16*)(wsp + 15802368);    // 2048x1024 bf16
    float* erase  = (float*)(wsp + 19996672);  // 2048x64 fp32
    float* add    = (float*)(wsp + 20520960);  // 2048x64 fp32
    u16*   rw_bf  = (u16*)(wsp + 21045248);    // 2048x1024 bf16
    u16*   rw2_bf = (u16*)(wsp + 25239552);    // 2048x1024 bf16
    float* s_buf  = (float*)(wsp + 29433856);  // 2048 fp32

    k_pre<<<3748, 256, 0, stream>>>(x, h_prev, rwp, memory, W_ih, W_hh, W_read, W_write,
                                    W_erase, W_add, W_out,
                                    inp_h, wcat, Wcat2, Wo_rn, memt, rp);
    k_gates<<<dim3(16, 32), 256, 0, stream>>>(inp_h, rp, wcat, b_ih, b_hh, c_prev, hrn);
    k_heads<<<dim3(16, 35), 256, 0, stream>>>(hrn, Wcat2, b_read, b_write, b_erase, b_add, b_out,
                                              pre_r, pre_w, erase, add, out);
    k_softmax<<<2048, 256, 0, stream>>>(pre_r, pre_w, rw_bf, rw2_bf, s_buf);
    k_rnout<<<dim3(64, 4), 256, 0, stream>>>(rw_bf, rw2_bf, memt, Wo_rn, erase, add, s_buf, out);
}